// Round 7
// baseline (239.241 us; speedup 1.0000x reference)
//
#include <hip/hip_runtime.h>
#include <math.h>

#define NUM_NODES 2000000
#define NUM_FLOPS 800000
#define NBX 168
#define NBY 480
#define NCK 8
#define NCE 8
#define YB_ROWS 30                 // y-bucket / tile granularity
#define NYB 16                     // y-buckets per column
#define NBUCK (NYB * NBX)          // 2,688 buckets; id = yb*NBX + col (cols contiguous)
#define CAPB 608                   // worst bucket (col 167 + halo) ~430 expected; +40% margin
#define ROWSTRIDE 68               // LDS acc row stride (64 + 4 pad)
#define CHUNK 1664                 // staged records per LDS pass (19,968 B)
#define MPT 8                      // flops per fill thread
#define FILL_BLOCKS 98             // 98*1024*8 = 802,816 >= NUM_FLOPS
#define S_INVSQRT2 0.7071067811865476f

// -------- workspace layout --------
// cnt : int   [NBUCK]            @ byte 0        (10.8 KB)
// rec : Rec12 [NBUCK * CAPB]     @ byte 10,752   (19.6 MB)   total < 20 MB
// (global scale array + gather kernel eliminated: out written by ff_main epilogue)

struct Rec12 { float cx, cy; int fke; };  // fke = (f << 12) | (rowrel << 6) | ke
// rowrel = by0 - bucket_yb*30 + 2, in [0,33]: primary [2,31], halo-down {0,1}, halo-up {32,33}

// Branch-free erf, Abramowitz-Stegun 7.1.26 (max abs err 1.5e-7); libm erff's
// divergent expf branch cost ~60 cyc/call (R5 back-computation).
__device__ __forceinline__ float fast_erf(float x) {
    float ax = fabsf(x);
    float t = __builtin_amdgcn_rcpf(fmaf(0.3275911f, ax, 1.0f));
    float p = t * fmaf(t, fmaf(t, fmaf(t, fmaf(t, 1.061405429f, -1.453152027f),
                                       1.421413741f), -0.284496736f), 0.254829592f);
    float r = fmaf(-p, __expf(-ax * ax), 1.0f);
    return copysignf(r, x);
}

__global__ void __launch_bounds__(1024)
ff_fill(const float* __restrict__ pos,
        const float* __restrict__ nsx,
        const float* __restrict__ nsy,
        const int* __restrict__ fi,
        const int* __restrict__ cs,
        int* __restrict__ cnt,
        Rec12* __restrict__ rec,
        float* __restrict__ out) {
    __shared__ int h[NBUCK];
    __shared__ int base[NBUCK];
    int tid = threadIdx.x;

    // fused: zero the output array (replaces a memset dispatch)
    int gt = blockIdx.x * 1024 + tid;
    for (int g = gt; g < NUM_NODES; g += FILL_BLOCKS * 1024) out[g] = 0.f;

    for (int j = tid; j < NBUCK; j += 1024) h[j] = 0;
    __syncthreads();

    float cx[MPT], cy[MPT];
    int fke[MPT], b1[MPT], r1[MPT], b2[MPT], r2[MPT];
    int f0 = blockIdx.x * (1024 * MPT);
#pragma unroll
    for (int m = 0; m < MPT; ++m) {
        int f = f0 + m * 1024 + tid;
        b1[m] = -1; b2[m] = -1;
        if (f < NUM_FLOPS) {
            int i = fi[f];
            float X = pos[i] + 0.5f * nsx[i];
            float Y = pos[NUM_NODES + i] + 0.5f * nsy[i];
            cx[m] = X; cy[m] = Y;
            int bx0 = (int)floorf(X); bx0 = bx0 < 0 ? 0 : (bx0 > NBX - 1 ? NBX - 1 : bx0);
            int by0 = (int)floorf(Y); by0 = by0 < 0 ? 0 : (by0 > NBY - 1 ? NBY - 1 : by0);
            int ke = cs[2 * f] * NCE + cs[2 * f + 1];
            int yb = by0 / YB_ROWS;
            int rlo = by0 - yb * YB_ROWS;
            fke[m] = (f << 12) | ((rlo + 2) << 6) | ke;       // rowrel vs primary bucket
            b1[m] = yb * NBX + bx0;
            r1[m] = atomicAdd(&h[b1[m]], 1);
            if (rlo <= 1 && yb > 0)             b2[m] = b1[m] - NBX;  // halo up: rowrel = rlo+32
            else if (rlo >= 28 && yb < NYB - 1) b2[m] = b1[m] + NBX;  // halo down: rowrel = rlo-28
            if (b2[m] >= 0) r2[m] = atomicAdd(&h[b2[m]], 1);
        }
    }
    __syncthreads();
    // merge into global counts; rotate sweep so blocks don't hit buckets in lockstep
    int off = (blockIdx.x * 911) % NBUCK;
    for (int j = tid; j < NBUCK; j += 1024) {
        int jj = j + off; if (jj >= NBUCK) jj -= NBUCK;
        base[jj] = h[jj] ? atomicAdd(&cnt[jj], h[jj]) : 0;
    }
    __syncthreads();
#pragma unroll
    for (int m = 0; m < MPT; ++m) {
        if (b1[m] >= 0) {
            Rec12 v; v.cx = cx[m]; v.cy = cy[m]; v.fke = fke[m];
            int s1 = base[b1[m]] + r1[m];
            if (s1 < CAPB) rec[(size_t)b1[m] * CAPB + s1] = v;
            if (b2[m] >= 0) {
                int rr = (b2[m] < b1[m]) ? ((fke[m] >> 6) & 63) + 30   // up: rlo+2+30
                                         : ((fke[m] >> 6) & 63) - 30;  // down: rlo+2-30
                Rec12 w; w.cx = cx[m]; w.cy = cy[m];
                w.fke = (fke[m] & ~(63 << 6)) | (rr << 6);
                int s2 = base[b2[m]] + r2[m];
                if (s2 < CAPB) rec[(size_t)b2[m] * CAPB + s2] = w;
            }
        }
    }
}

// Block (col,yb): stage <=5 neighbor buckets into LDS, accumulate 30x64 demand
// tile via LDS atomics, fused quantize reduce, then write out[] for the center
// bucket's primary records (gather kernel eliminated).
__global__ void __launch_bounds__(256)
ff_main(const int* __restrict__ cnt,
        const Rec12* __restrict__ rec,
        const int* __restrict__ fi,
        float* __restrict__ out) {
    __shared__ float acc[YB_ROWS * ROWSTRIDE];   // 8,160 B
    __shared__ float stage[CHUNK * 3];           // 19,968 B
    __shared__ float srow[YB_ROWS];
    int tid = threadIdx.x;
    int col = blockIdx.x;
    int yb = blockIdx.y;
    int y0 = yb * YB_ROWS;

    for (int j = tid; j < YB_ROWS * ROWSTRIDE; j += 256) acc[j] = 0.f;

    int c_lo = col - 2 < 0 ? 0 : col - 2;
    int c_hi = col + 2 > NBX - 1 ? NBX - 1 : col + 2;
    int nb = c_hi - c_lo + 1;
    int start[6];
    start[0] = 0;
    for (int k = 0; k < nb; ++k) {
        int n = cnt[yb * NBX + c_lo + k];
        n = n < CAPB ? n : CAPB;
        start[k + 1] = start[k] + n;
    }
    int tot = start[nb];
    const Rec12* bb = rec + (size_t)(yb * NBX + c_lo) * CAPB;
    float cf = (float)col;
    __syncthreads();

    for (int c0 = 0; c0 < tot; c0 += CHUNK) {
        int m = tot - c0; m = m < CHUNK ? m : CHUNK;
        // bulk staging: many independent loads in flight -> latency amortized
        for (int r = tid; r < m; r += 256) {
            int g = c0 + r;
            int k = 0;
#pragma unroll
            for (int t = 1; t < 5; ++t) k += (t < nb && g >= start[t]) ? 1 : 0;
            Rec12 v = bb[(size_t)k * CAPB + (g - start[k])];
            stage[r * 3]     = v.cx;
            stage[r * 3 + 1] = v.cy;
            stage[r * 3 + 2] = __int_as_float(v.fke);
        }
        __syncthreads();
        for (int r = tid; r < m; r += 256) {
            float cx = stage[r * 3];
            float cy = stage[r * 3 + 1];
            int fke = __float_as_int(stage[r * 3 + 2]);
            int ke = fke & 63;
            int by0 = y0 + ((fke >> 6) & 63) - 2;     // rowrel relative to this yb
            float dx = 0.5f * (fast_erf((cf + 1.f - cx) * S_INVSQRT2) -
                               fast_erf((cf - cx) * S_INVSQRT2));
            float e_prev = fast_erf(((float)(by0 - 2) - cy) * S_INVSQRT2);
#pragma unroll
            for (int j = 0; j < 5; ++j) {
                int by = by0 - 2 + j;
                float e_next = fast_erf(((float)(by + 1) - cy) * S_INVSQRT2);
                int row = by - y0;
                int rowc = row < 0 ? 0 : (row > YB_ROWS - 1 ? YB_ROWS - 1 : row);
                float d = (row == rowc) ? dx * 0.5f * (e_next - e_prev) : 0.f;
                atomicAdd(&acc[rowc * ROWSTRIDE + ke], d);   // unconditional, no exec-mask dance
                e_prev = e_next;
            }
        }
        __syncthreads();
    }

    // fused quantization reduce: one thread per owned row
    if (tid < YB_ROWS) {
        const float4* p = (const float4*)(acc + tid * ROWSTRIDE);
        float tot2 = 0.f, halves = 0.f;
#pragma unroll
        for (int ck = 0; ck < NCK; ++ck) {
            float q = 0.f;
#pragma unroll
            for (int v = 0; v < 2; ++v) {
                float4 d = p[ck * 2 + v];
                tot2 += d.x + d.y + d.z + d.w;
                q += ceilf(d.x * 0.25f) + ceilf(d.y * 0.25f) +
                     ceilf(d.z * 0.25f) + ceilf(d.w * 0.25f);
            }
            halves += ceilf(0.5f * q);
        }
        float slices = ceilf(0.5f * halves);
        srow[tid] = (tot2 > 0.f) ? (slices / fmaxf(tot2, 1e-12f)) : 0.f;
    }
    __syncthreads();

    // epilogue: write out[] for this block's center bucket (primary records only)
    int cb = yb * NBX + col;
    int nc = cnt[cb]; nc = nc < CAPB ? nc : CAPB;
    const Rec12* cbp = rec + (size_t)cb * CAPB;
    for (int r = tid; r < nc; r += 256) {
        int fke = cbp[r].fke;
        int rowrel = (fke >> 6) & 63;
        if (rowrel >= 2 && rowrel <= 31) {            // skip y-halo copies
            int f = ((unsigned)fke) >> 12;
            out[fi[f]] = srow[rowrel - 2];
        }
    }
}

extern "C" void kernel_launch(void* const* d_in, const int* in_sizes, int n_in,
                              void* d_out, int out_size, void* d_ws, size_t ws_size,
                              hipStream_t stream) {
    const float* pos = (const float*)d_in[0];
    const float* nsx = (const float*)d_in[1];
    const float* nsy = (const float*)d_in[2];
    const int*   fi  = (const int*)d_in[3];
    const int*   cs  = (const int*)d_in[4];
    float* out = (float*)d_out;

    int*   cnt = (int*)d_ws;
    Rec12* rec = (Rec12*)((char*)d_ws + NBUCK * sizeof(int));

    hipMemsetAsync(cnt, 0, NBUCK * sizeof(int), stream);

    ff_fill<<<FILL_BLOCKS, 1024, 0, stream>>>(pos, nsx, nsy, fi, cs, cnt, rec, out);
    ff_main<<<dim3(NBX, NYB), 256, 0, stream>>>(cnt, rec, fi, out);
}

// Round 8
// 238.469 us; speedup vs baseline: 1.0032x; 1.0032x over previous
//
#include <hip/hip_runtime.h>
#include <math.h>

#define NUM_NODES 2000000
#define NUM_FLOPS 800000
#define NBX 168
#define NBY 480
#define NCK 8
#define NCE 8
#define NBINS (NBX * NBY)          // 80,640
#define YB_ROWS 30                 // y-bucket / tile granularity
#define NYB 16                     // y-buckets per column
#define NBUCK (NYB * NBX)          // 2,688 buckets; id = yb*NBX + col (cols contiguous)
#define CAPB 536                   // worst bucket (col167) ~430 expected + 5sigma(~105)
#define ROWSTRIDE 68               // LDS acc row stride (64 + 4 pad)
#define BS 512                     // ff_main block: 8 waves -> 4 blocks/CU = 32 waves/CU
#define S_INVSQRT2 0.7071067811865476f
#define FILL_THREADS (784 * 1024)

// -------- workspace layout --------
// scale    : float [NBINS]            @ 0            (322.6 KB)
// cnt      : int   [NBUCK]            @ +NBINS       (10.8 KB)
// bin_of_f : int   [NUM_FLOPS]        @ +NBUCK       (3.2 MB)
// rec      : Rec12 [NBUCK * CAPB]     @ 16B-aligned  (17.29 MB)
// total 20.82 MB (< 20.97 MB proven in R1)

struct Rec12 { float cx, cy; int fke; };  // fke = (f << 12) | (rowrel << 6) | ke
// rowrel = by0 - bucket_yb*30 + 2 in [0,33]

__device__ __forceinline__ float fast_erf(float x) {
    float ax = fabsf(x);
    float t = __builtin_amdgcn_rcpf(fmaf(0.3275911f, ax, 1.0f));
    float p = t * fmaf(t, fmaf(t, fmaf(t, fmaf(t, 1.061405429f, -1.453152027f),
                                       1.421413741f), -0.284496736f), 0.254829592f);
    float r = fmaf(-p, __expf(-ax * ax), 1.0f);
    return copysignf(r, x);
}

__global__ void __launch_bounds__(1024)
ff_fill(const float* __restrict__ pos,
        const float* __restrict__ nsx,
        const float* __restrict__ nsy,
        const int* __restrict__ fi,
        const int* __restrict__ cs,
        int* __restrict__ cnt,
        int* __restrict__ bin_of_f,
        Rec12* __restrict__ rec,
        float* __restrict__ out) {
    __shared__ int h[NBUCK];
    __shared__ int base[NBUCK];
    int tid = threadIdx.x;
    int f = blockIdx.x * 1024 + tid;

    // fused: zero the output array (replaces a memset dispatch)
    for (int g = f; g < NUM_NODES; g += FILL_THREADS) out[g] = 0.f;

    for (int j = tid; j < NBUCK; j += 1024) h[j] = 0;
    __syncthreads();

    bool valid = (f < NUM_FLOPS);
    int b1 = 0, b2 = -1, r1 = 0, r2 = 0, fke = 0;
    float cx = 0.f, cy = 0.f;
    if (valid) {
        int i = fi[f];
        cx = pos[i] + 0.5f * nsx[i];
        cy = pos[NUM_NODES + i] + 0.5f * nsy[i];
        int bx0 = (int)floorf(cx); bx0 = bx0 < 0 ? 0 : (bx0 > NBX - 1 ? NBX - 1 : bx0);
        int by0 = (int)floorf(cy); by0 = by0 < 0 ? 0 : (by0 > NBY - 1 ? NBY - 1 : by0);
        int ke = cs[2 * f] * NCE + cs[2 * f + 1];
        int yb = by0 / YB_ROWS;
        int rlo = by0 - yb * YB_ROWS;
        fke = (f << 12) | ((rlo + 2) << 6) | ke;
        b1 = yb * NBX + bx0;
        bin_of_f[f] = bx0 * NBY + by0;
        r1 = atomicAdd(&h[b1], 1);
        if (rlo <= 1 && yb > 0)             b2 = b1 - NBX;  // halo up
        else if (rlo >= 28 && yb < NYB - 1) b2 = b1 + NBX;  // halo down
        if (b2 >= 0) r2 = atomicAdd(&h[b2], 1);
    }
    __syncthreads();
    for (int j = tid; j < NBUCK; j += 1024)
        base[j] = h[j] ? atomicAdd(&cnt[j], h[j]) : 0;
    __syncthreads();
    if (valid) {
        Rec12 v; v.cx = cx; v.cy = cy; v.fke = fke;
        int s1 = base[b1] + r1;
        if (s1 < CAPB) rec[(size_t)b1 * CAPB + s1] = v;
        if (b2 >= 0) {
            int rr = (b2 < b1) ? ((fke >> 6) & 63) + 30 : ((fke >> 6) & 63) - 30;
            Rec12 w; w.cx = cx; w.cy = cy;
            w.fke = (fke & ~(63 << 6)) | (rr << 6);
            int s2 = base[b2] + r2;
            if (s2 < CAPB) rec[(size_t)b2 * CAPB + s2] = w;
        }
    }
}

__device__ __forceinline__ void visit(float cx, float cy, int fke,
                                      float cf, float* acc) {
    int ke = fke & 63;
    int rbase = ((fke >> 6) & 63) - 4;      // first cell row (rowrel - 2 - 2)
    float dx = 0.5f * (fast_erf((cf + 1.f - cx) * S_INVSQRT2) -
                       fast_erf((cf - cx) * S_INVSQRT2));
    float yb0 = (float)rbase - 2.f - cy;    // wrong? edge0 = y0+rbase - cy, y0 folded below
    // edges are absolute: by0-2 .. by0+3; rbase is row-relative, rows = y0+rbase+j.
    // cy passed in already y0-relative (caller subtracts y0), so edge j = rbase + j - cy_rel.
    float e0 = fast_erf(((float)(rbase + 0) - cy) * S_INVSQRT2);
    float e1 = fast_erf(((float)(rbase + 1) - cy) * S_INVSQRT2);
    float e2 = fast_erf(((float)(rbase + 2) - cy) * S_INVSQRT2);
    float e3 = fast_erf(((float)(rbase + 3) - cy) * S_INVSQRT2);
    float e4 = fast_erf(((float)(rbase + 4) - cy) * S_INVSQRT2);
    float e5 = fast_erf(((float)(rbase + 5) - cy) * S_INVSQRT2);
    float d0 = dx * 0.5f * (e1 - e0);
    float d1 = dx * 0.5f * (e2 - e1);
    float d2 = dx * 0.5f * (e3 - e2);
    float d3 = dx * 0.5f * (e4 - e3);
    float d4 = dx * 0.5f * (e5 - e4);
    (void)yb0;
    int r0 = rbase;
    if ((unsigned)(r0 + 0) < YB_ROWS) atomicAdd(&acc[(r0 + 0) * ROWSTRIDE + ke], d0);
    if ((unsigned)(r0 + 1) < YB_ROWS) atomicAdd(&acc[(r0 + 1) * ROWSTRIDE + ke], d1);
    if ((unsigned)(r0 + 2) < YB_ROWS) atomicAdd(&acc[(r0 + 2) * ROWSTRIDE + ke], d2);
    if ((unsigned)(r0 + 3) < YB_ROWS) atomicAdd(&acc[(r0 + 3) * ROWSTRIDE + ke], d3);
    if ((unsigned)(r0 + 4) < YB_ROWS) atomicAdd(&acc[(r0 + 4) * ROWSTRIDE + ke], d4);
}

// Block (col,yb): 30x64 LDS demand tile; 8 waves/block, 2-way record interleave
// for MLP/ILP (latency-bound per R5-R7 analysis). Fused quantize reduce.
__global__ void __launch_bounds__(BS)
ff_main(const int* __restrict__ cnt,
        const Rec12* __restrict__ rec,
        float* __restrict__ scale) {
    __shared__ float acc[YB_ROWS * ROWSTRIDE];   // 8,160 B
    int tid = threadIdx.x;
    int col = blockIdx.x;
    int yb = blockIdx.y;
    float y0f = (float)(yb * YB_ROWS);

    for (int j = tid; j < YB_ROWS * ROWSTRIDE; j += BS) acc[j] = 0.f;

    int c_lo = col - 2 < 0 ? 0 : col - 2;
    int c_hi = col + 2 > NBX - 1 ? NBX - 1 : col + 2;
    int nb = c_hi - c_lo + 1;
    int start[6];
    start[0] = 0;
    for (int k = 0; k < nb; ++k) {
        int n = cnt[yb * NBX + c_lo + k];
        n = n < CAPB ? n : CAPB;
        start[k + 1] = start[k] + n;
    }
    int tot = start[nb];
    const Rec12* bb = rec + (size_t)(yb * NBX + c_lo) * CAPB;
    float cf = (float)col;
    __syncthreads();

    for (int idx = tid; idx < tot; idx += 2 * BS) {
        int i1 = idx + BS;
        bool has1 = i1 < tot;
        int k0 = 0, k1 = 0;
#pragma unroll
        for (int t = 1; t < 5; ++t) {
            k0 += (t < nb && idx >= start[t]) ? 1 : 0;
            k1 += (t < nb && i1  >= start[t]) ? 1 : 0;
        }
        // two independent loads in flight
        Rec12 v0 = bb[(size_t)k0 * CAPB + (idx - start[k0])];
        Rec12 v1 = has1 ? bb[(size_t)k1 * CAPB + (i1 - start[k1])] : v0;
        // two independent erf chains; compiler interleaves
        visit(v0.cx, v0.cy - y0f, v0.fke, cf, acc);
        if (has1) visit(v1.cx, v1.cy - y0f, v1.fke, cf, acc);
    }
    __syncthreads();

    if (tid < YB_ROWS) {
        const float4* p = (const float4*)(acc + tid * ROWSTRIDE);
        float tot2 = 0.f, halves = 0.f;
#pragma unroll
        for (int ck = 0; ck < NCK; ++ck) {
            float q = 0.f;
#pragma unroll
            for (int v = 0; v < 2; ++v) {
                float4 d = p[ck * 2 + v];
                tot2 += d.x + d.y + d.z + d.w;
                q += ceilf(d.x * 0.25f) + ceilf(d.y * 0.25f) +
                     ceilf(d.z * 0.25f) + ceilf(d.w * 0.25f);
            }
            halves += ceilf(0.5f * q);
        }
        float slices = ceilf(0.5f * halves);
        scale[col * NBY + yb * YB_ROWS + tid] =
            (tot2 > 0.f) ? (slices / fmaxf(tot2, 1e-12f)) : 0.f;
    }
}

__global__ void ff_gather(const int* __restrict__ fi,
                          const int* __restrict__ bin_of_f,
                          const float* __restrict__ scale,
                          float* __restrict__ out) {
    int f = blockIdx.x * blockDim.x + threadIdx.x;
    if (f >= NUM_FLOPS) return;
    out[fi[f]] = scale[bin_of_f[f]];
}

extern "C" void kernel_launch(void* const* d_in, const int* in_sizes, int n_in,
                              void* d_out, int out_size, void* d_ws, size_t ws_size,
                              hipStream_t stream) {
    const float* pos = (const float*)d_in[0];
    const float* nsx = (const float*)d_in[1];
    const float* nsy = (const float*)d_in[2];
    const int*   fi  = (const int*)d_in[3];
    const int*   cs  = (const int*)d_in[4];
    float* out = (float*)d_out;

    float* scale    = (float*)d_ws;
    int*   cnt      = (int*)(scale + NBINS);
    int*   bin_of_f = cnt + NBUCK;
    Rec12* rec      = (Rec12*)(bin_of_f + NUM_FLOPS);

    hipMemsetAsync(cnt, 0, NBUCK * sizeof(int), stream);

    ff_fill<<<784, 1024, 0, stream>>>(pos, nsx, nsy, fi, cs, cnt, bin_of_f, rec, out);
    ff_main<<<dim3(NBX, NYB), BS, 0, stream>>>(cnt, rec, scale);
    ff_gather<<<(NUM_FLOPS + 255) / 256, 256, 0, stream>>>(fi, bin_of_f, scale, out);
}

// Round 10
// 231.666 us; speedup vs baseline: 1.0327x; 1.0294x over previous
//
#include <hip/hip_runtime.h>
#include <math.h>

#define NUM_NODES 2000000
#define NUM_FLOPS 800000
#define NBX 168
#define NBY 480
#define NCK 8
#define NCE 8
#define NBINS (NBX * NBY)
#define YB_ROWS 30                 // y-bucket / tile row granularity
#define NYB 16
#define NBUCK (NYB * NBX)          // 2,688 buckets; id = yb*NBX + col
#define CAPB 536                   // worst bucket ~430 expected + 5sigma (ran clean R8)
#define TC 4                       // tile columns per main block
#define NTX (NBX / TC)             // 42
#define NSCAN 8                    // buckets scanned: C0-2 .. C0+5 (window +-2 around 4 cols)
#define ACCSTRIDE 66               // floats per (col,row) cell group (64 + 2 pad)
#define BS 512
#define MPT 8
#define FILL_BLOCKS 98             // 98*1024*8 = 802,816 >= NUM_FLOPS
#define S_INVSQRT2 0.7071067811865476f

// -------- workspace layout --------
// scale    : float [NBINS]        @ 0           (322.6 KB)
// cnt      : int   [NBUCK]        @ +NBINS      (10.8 KB)
// bin_of_f : int   [NUM_FLOPS]    @ +NBUCK      (3.2 MB)
// rec      : Rec12 [NBUCK*CAPB]                 (17.3 MB)   total 20.8 MB (fits, ran R8)

struct Rec12 { float cx, cy; int fke; };  // fke = (rowrel << 6) | ke, rowrel in [0,33]

// Branch-free erf, Abramowitz-Stegun 7.1.26 (max abs err 1.5e-7)
__device__ __forceinline__ float fast_erf(float x) {
    float ax = fabsf(x);
    float t = __builtin_amdgcn_rcpf(fmaf(0.3275911f, ax, 1.0f));
    float p = t * fmaf(t, fmaf(t, fmaf(t, fmaf(t, 1.061405429f, -1.453152027f),
                                       1.421413741f), -0.284496736f), 0.254829592f);
    float r = fmaf(-p, __expf(-ax * ax), 1.0f);
    return copysignf(r, x);
}

__global__ void __launch_bounds__(1024)
ff_fill(const float* __restrict__ pos,
        const float* __restrict__ nsx,
        const float* __restrict__ nsy,
        const int* __restrict__ fi,
        const int* __restrict__ cs,
        int* __restrict__ cnt,
        int* __restrict__ bin_of_f,
        Rec12* __restrict__ rec,
        float* __restrict__ out) {
    __shared__ int h[NBUCK];
    __shared__ int base[NBUCK];
    int tid = threadIdx.x;

    // fused: zero the output array (replaces a memset dispatch)
    for (int g = blockIdx.x * 1024 + tid; g < NUM_NODES; g += FILL_BLOCKS * 1024)
        out[g] = 0.f;

    for (int j = tid; j < NBUCK; j += 1024) h[j] = 0;
    __syncthreads();

    float cx[MPT], cy[MPT];
    int fke[MPT], b1[MPT], r1[MPT], b2[MPT], r2[MPT];
    int f0 = blockIdx.x * (1024 * MPT);
#pragma unroll
    for (int m = 0; m < MPT; ++m) {
        int f = f0 + m * 1024 + tid;
        b1[m] = -1; b2[m] = -1;
        if (f < NUM_FLOPS) {
            int i = fi[f];
            float X = pos[i] + 0.5f * nsx[i];
            float Y = pos[NUM_NODES + i] + 0.5f * nsy[i];
            cx[m] = X; cy[m] = Y;
            int bx0 = (int)floorf(X); bx0 = bx0 < 0 ? 0 : (bx0 > NBX - 1 ? NBX - 1 : bx0);
            int by0 = (int)floorf(Y); by0 = by0 < 0 ? 0 : (by0 > NBY - 1 ? NBY - 1 : by0);
            int ke = cs[2 * f] * NCE + cs[2 * f + 1];
            int yb = by0 / YB_ROWS;
            int rlo = by0 - yb * YB_ROWS;
            fke[m] = ((rlo + 2) << 6) | ke;
            b1[m] = yb * NBX + bx0;
            bin_of_f[f] = bx0 * NBY + by0;
            r1[m] = atomicAdd(&h[b1[m]], 1);
            if (rlo <= 1 && yb > 0)             b2[m] = b1[m] - NBX;  // halo up
            else if (rlo >= 28 && yb < NYB - 1) b2[m] = b1[m] + NBX;  // halo down
            if (b2[m] >= 0) r2[m] = atomicAdd(&h[b2[m]], 1);
        }
    }
    __syncthreads();
    // global merge: ~2500 nonzero buckets per block x 98 blocks = ~245K atomics
    int off = (blockIdx.x * 911) % NBUCK;
    for (int j = tid; j < NBUCK; j += 1024) {
        int jj = j + off; if (jj >= NBUCK) jj -= NBUCK;
        base[jj] = h[jj] ? atomicAdd(&cnt[jj], h[jj]) : 0;
    }
    __syncthreads();
#pragma unroll
    for (int m = 0; m < MPT; ++m) {
        if (b1[m] >= 0) {
            Rec12 v; v.cx = cx[m]; v.cy = cy[m]; v.fke = fke[m];
            int s1 = base[b1[m]] + r1[m];
            if (s1 < CAPB) rec[(size_t)b1[m] * CAPB + s1] = v;
            if (b2[m] >= 0) {
                int rr = (b2[m] < b1[m]) ? ((fke[m] >> 6) & 63) + 30
                                         : ((fke[m] >> 6) & 63) - 30;
                Rec12 w; w.cx = cx[m]; w.cy = cy[m]; w.fke = (fke[m] & 63) | (rr << 6);
                int s2 = base[b2[m]] + r2[m];
                if (s2 < CAPB) rec[(size_t)b2[m] * CAPB + s2] = w;
            }
        }
    }
}

// Block owns a 4-col x 30-row x 64-ke LDS tile. Scans the 8 buckets C0-2..C0+5
// (every bx0 whose +-2 window touches the tile — R9 scanned only 6 and dropped
// demand). Each record loaded ONCE; 12 erf edges computed ONCE, shared across
// the <=4 in-tile columns. Fused quantize reduce.
__global__ void __launch_bounds__(BS)
ff_main(const int* __restrict__ cnt,
        const Rec12* __restrict__ rec,
        float* __restrict__ scale) {
    __shared__ float acc[TC * YB_ROWS * ACCSTRIDE];   // 31,680 B
    int tid = threadIdx.x;
    int C0 = blockIdx.x * TC;
    int yb = blockIdx.y;
    int y0 = yb * YB_ROWS;

    for (int j = tid; j < TC * YB_ROWS * ACCSTRIDE; j += BS) acc[j] = 0.f;

    int start[NSCAN + 1];
    size_t kbase[NSCAN];
    start[0] = 0;
    for (int k = 0; k < NSCAN; ++k) {
        int c = C0 - 2 + k;
        int n = 0;
        if ((unsigned)c < (unsigned)NBX) {
            n = cnt[yb * NBX + c];
            n = n < CAPB ? n : CAPB;
        }
        kbase[k] = (size_t)(yb * NBX + ((unsigned)c < (unsigned)NBX ? c : 0)) * CAPB;
        start[k + 1] = start[k] + n;
    }
    int tot = start[NSCAN];
    __syncthreads();

    for (int idx = tid; idx < tot; idx += BS) {
        int k = 0;
#pragma unroll
        for (int t = 1; t < NSCAN; ++t) k += (idx >= start[t]) ? 1 : 0;
        Rec12 v = rec[kbase[k] + (idx - start[k])];
        int ke = v.fke & 63;
        int rbase = ((v.fke >> 6) & 63) - 4;        // tile-relative first cell row
        int bx0 = C0 - 2 + k;                       // bucket col == record's bx0

        float fx0 = (float)(bx0 - 2) - v.cx;        // x edge 0 (in (-3,-2])
        float ex0 = fast_erf(fx0 * S_INVSQRT2);
        float ex1 = fast_erf((fx0 + 1.f) * S_INVSQRT2);
        float ex2 = fast_erf((fx0 + 2.f) * S_INVSQRT2);
        float ex3 = fast_erf((fx0 + 3.f) * S_INVSQRT2);
        float ex4 = fast_erf((fx0 + 4.f) * S_INVSQRT2);
        float ex5 = fast_erf((fx0 + 5.f) * S_INVSQRT2);
        float fy0 = (float)rbase - (v.cy - (float)y0);   // y edge 0 (in [-3,-2))
        float ey0 = fast_erf(fy0 * S_INVSQRT2);
        float ey1 = fast_erf((fy0 + 1.f) * S_INVSQRT2);
        float ey2 = fast_erf((fy0 + 2.f) * S_INVSQRT2);
        float ey3 = fast_erf((fy0 + 3.f) * S_INVSQRT2);
        float ey4 = fast_erf((fy0 + 4.f) * S_INVSQRT2);
        float ey5 = fast_erf((fy0 + 5.f) * S_INVSQRT2);
        float wy0 = 0.5f * (ey1 - ey0);
        float wy1 = 0.5f * (ey2 - ey1);
        float wy2 = 0.5f * (ey3 - ey2);
        float wy3 = 0.5f * (ey4 - ey3);
        float wy4 = 0.5f * (ey5 - ey4);
        float exv[6] = {ex0, ex1, ex2, ex3, ex4, ex5};

#pragma unroll
        for (int cc = 0; cc < TC; ++cc) {
            int i = cc - k + 4;                     // x-weight index for col C0+cc
            if ((unsigned)i <= 4u) {
                float dx = 0.5f * (exv[i + 1] - exv[i]);
                float* ab = acc + (cc * YB_ROWS) * ACCSTRIDE + ke;
#pragma unroll
                for (int j = 0; j < 5; ++j) {
                    int row = rbase + j;
                    float w = (j == 0) ? wy0 : (j == 1) ? wy1 : (j == 2) ? wy2
                              : (j == 3) ? wy3 : wy4;
                    if ((unsigned)row < YB_ROWS)
                        atomicAdd(ab + row * ACCSTRIDE, dx * w);
                }
            }
        }
    }
    __syncthreads();

    // fused quantization reduce: threads 0..119 each own one (col,row) bin
    if (tid < TC * YB_ROWS) {
        int cc = tid / YB_ROWS, r = tid - cc * YB_ROWS;
        const float* p = acc + (cc * YB_ROWS + r) * ACCSTRIDE;
        float tot2 = 0.f, halves = 0.f;
#pragma unroll
        for (int ck = 0; ck < NCK; ++ck) {
            float q = 0.f;
#pragma unroll
            for (int e = 0; e < NCE; ++e) {
                float d = p[ck * NCE + e];
                tot2 += d;
                q += ceilf(d * 0.25f);
            }
            halves += ceilf(0.5f * q);
        }
        float slices = ceilf(0.5f * halves);
        scale[(C0 + cc) * NBY + y0 + r] = (tot2 > 0.f) ? (slices / fmaxf(tot2, 1e-12f)) : 0.f;
    }
}

__global__ void ff_gather(const int* __restrict__ fi,
                          const int* __restrict__ bin_of_f,
                          const float* __restrict__ scale,
                          float* __restrict__ out) {
    int f = blockIdx.x * blockDim.x + threadIdx.x;
    if (f >= NUM_FLOPS) return;
    out[fi[f]] = scale[bin_of_f[f]];
}

extern "C" void kernel_launch(void* const* d_in, const int* in_sizes, int n_in,
                              void* d_out, int out_size, void* d_ws, size_t ws_size,
                              hipStream_t stream) {
    const float* pos = (const float*)d_in[0];
    const float* nsx = (const float*)d_in[1];
    const float* nsy = (const float*)d_in[2];
    const int*   fi  = (const int*)d_in[3];
    const int*   cs  = (const int*)d_in[4];
    float* out = (float*)d_out;

    float* scale    = (float*)d_ws;
    int*   cnt      = (int*)(scale + NBINS);
    int*   bin_of_f = cnt + NBUCK;
    Rec12* rec      = (Rec12*)(bin_of_f + NUM_FLOPS);

    hipMemsetAsync(cnt, 0, NBUCK * sizeof(int), stream);

    ff_fill<<<FILL_BLOCKS, 1024, 0, stream>>>(pos, nsx, nsy, fi, cs,
                                              cnt, bin_of_f, rec, out);
    ff_main<<<dim3(NTX, NYB), BS, 0, stream>>>(cnt, rec, scale);
    ff_gather<<<(NUM_FLOPS + 255) / 256, 256, 0, stream>>>(fi, bin_of_f, scale, out);
}